// Round 4
// baseline (216.381 us; speedup 1.0000x reference)
//
#include <hip/hip_runtime.h>
#include <hip/hip_bf16.h>

#define B_ 16
#define N_ 8192
#define C_ 512
#define H_ 8
#define HD_ 64
#define CH_ 32

// ws float layout:
//   [0, 512)          qfull (cls@Wq * scale)
//   [512, 4608)       qk[h][c]  (8 x 512)
//   [4608, 4736)      Linv[b][h]  (16 x 8)
//   [4736, 70272)     aa[b][h][c] unnormalized weighted sums (16 x 8 x 512)
//   [70272, 86656)    pp[half][b][o] partial pooled (2 x 16 x 512)
//   [86656, ...)      partials: per (b,chunk): { l[8], acc[8*512] } stride 4104
#define WS_QK   512
#define WS_LINV 4608
#define WS_AA   4736
#define WS_PP   70272
#define WS_PART 86656

// ---------------- K1: qfull = cls @ Wq * HD^-0.5 ----------------
__global__ void k_qfull(const float* __restrict__ cls, const float* __restrict__ Wq,
                        float* __restrict__ ws) {
    __shared__ float red[256];
    int t = threadIdx.x;
    int o = blockIdx.x * 64 + (t & 63);
    int q = t >> 6;  // 0..3
    float p = 0.f;
    for (int c = q * 128; c < q * 128 + 128; ++c)
        p += cls[c] * Wq[c * C_ + o];
    red[t] = p;
    __syncthreads();
    if (t < 64) {
        float s = red[t] + red[t + 64] + red[t + 128] + red[t + 192];
        ws[o] = s * 0.125f;  // HD^-0.5 = 1/8
    }
}

// ---------------- K2: qk[h][c] = sum_d Wk[c, h*64+d] * qfull[h*64+d] ----------------
__global__ void k_qk(const float* __restrict__ Wk, float* __restrict__ ws) {
    __shared__ float wrow[8 * 520];  // 8 rows of Wk, padded stride
    __shared__ float qf[512];
    int t = threadIdx.x;
    int c0 = blockIdx.x * 8;
    int r = t >> 5;             // 8 rows, 32 threads each
    int col = (t & 31) * 16;    // 16 floats per thread
    const float4* src = (const float4*)(Wk + (size_t)(c0 + r) * C_ + col);
    float4* dst = (float4*)(&wrow[r * 520 + col]);
    dst[0] = src[0]; dst[1] = src[1]; dst[2] = src[2]; dst[3] = src[3];
    if (t < 128) ((float4*)qf)[t] = ((const float4*)ws)[t];
    __syncthreads();
    if (t < 64) {
        int h = t >> 3, cc = t & 7;
        const float* wr = &wrow[cc * 520 + h * 64];
        const float* qh = &qf[h * 64];
        float s = 0.f;
#pragma unroll
        for (int d = 0; d < 64; ++d) s += wr[d] * qh[d];
        ws[WS_QK + h * C_ + c0 + cc] = s;
    }
}

// ---------------- K3: main streaming pass over x ----------------
// Head-split + row-batch-4 redesign (round 4):
//   waves 0,1 handle heads 0-3; waves 2,3 handle heads 4-7.
//   waves 0,2 process rows [0,128), waves 1,3 rows [128,256) of the chunk
//   (paired waves share rows -> L1 reuse; HBM traffic unchanged).
//   Per lane: cols 4L..4L+3 and 256+4L..+3. qr/acc are 4 heads x 8 cols.
//   4 rows are batched through one interleaved folded butterfly so the 4
//   DS-chain latencies overlap (round 1-3 were serialized per-row: ~2800
//   cyc/row measured; this should cut to ~400-600 cyc/row).
// Folded butterfly (4 heads): after stages xor1,xor2 lane holds head
// f(L)=2*b0+b1 summed over 4-lane group; then plain xor 4..32 completes the
// 64-lane sum. Source lane for head j is bitrev2(j) = (j>>1)|((j&1)<<1).
__global__ __launch_bounds__(256) void k_main(const float* __restrict__ x,
                                              const float* __restrict__ ws,
                                              float* __restrict__ part, int CH) {
    int blk = blockIdx.x;
    int b = blk / CH, chunk = blk % CH;
    int lane = threadIdx.x & 63, wave = threadIdx.x >> 6;
    int q = wave & 1;        // row half
    int g = wave >> 1;       // head group: heads 4g..4g+3
    int rpb = N_ / CH;       // rows per block (256)
    int hrows = rpb >> 1;    // rows per wave (128)
    int n0 = chunk * rpb + q * hrows;

    const float* qk = ws + WS_QK;
    int lo = 4 * lane, hi = 256 + 4 * lane;

    float qr[4][8];
#pragma unroll
    for (int j = 0; j < 4; ++j) {
        int h = 4 * g + j;
        float4 a = *(const float4*)(qk + h * C_ + lo);
        float4 bb = *(const float4*)(qk + h * C_ + hi);
        qr[j][0] = a.x;  qr[j][1] = a.y;  qr[j][2] = a.z;  qr[j][3] = a.w;
        qr[j][4] = bb.x; qr[j][5] = bb.y; qr[j][6] = bb.z; qr[j][7] = bb.w;
    }

    float acc[4][8];
#pragma unroll
    for (int j = 0; j < 4; ++j)
#pragma unroll
        for (int c = 0; c < 8; ++c) acc[j][c] = 0.f;
    float lsum = 0.f;

    const float* xp = x + ((size_t)b * N_ + n0) * C_;
    int b0 = lane & 1, b1 = lane & 2;

    // process a batch of 4 staged rows
    auto process = [&](const float4 (&R)[4][2]) {
        float xv[4][8];
#pragma unroll
        for (int r = 0; r < 4; ++r) {
            xv[r][0] = R[r][0].x; xv[r][1] = R[r][0].y;
            xv[r][2] = R[r][0].z; xv[r][3] = R[r][0].w;
            xv[r][4] = R[r][1].x; xv[r][5] = R[r][1].y;
            xv[r][6] = R[r][1].z; xv[r][7] = R[r][1].w;
        }
        float p[4][4];
#pragma unroll
        for (int r = 0; r < 4; ++r)
#pragma unroll
            for (int j = 0; j < 4; ++j) {
                float s = xv[r][0] * qr[j][0];
#pragma unroll
                for (int c = 1; c < 8; ++c) s = fmaf(xv[r][c], qr[j][c], s);
                p[r][j] = s;
            }
        // stage 1 (xor1, fold head bit1) - 4 rows interleaved
        float t2[4][2];
#pragma unroll
        for (int i = 0; i < 2; ++i)
#pragma unroll
            for (int r = 0; r < 4; ++r) {
                float send = b0 ? p[r][i] : p[r][i + 2];
                float recv = __shfl_xor(send, 1, 64);
                t2[r][i] = (b0 ? p[r][i + 2] : p[r][i]) + recv;
            }
        // stage 2 (xor2, fold head bit0)
        float u[4];
#pragma unroll
        for (int r = 0; r < 4; ++r) {
            float send = b1 ? t2[r][0] : t2[r][1];
            float recv = __shfl_xor(send, 2, 64);
            u[r] = (b1 ? t2[r][1] : t2[r][0]) + recv;
        }
        // stages xor4..xor32, rows interleaved so chains overlap
#pragma unroll
        for (int st = 4; st < 64; st <<= 1)
#pragma unroll
            for (int r = 0; r < 4; ++r) u[r] += __shfl_xor(u[r], st, 64);
        // exp + accumulate
#pragma unroll
        for (int r = 0; r < 4; ++r) {
            float e = __expf(u[r]);  // logits O(1): un-normalized softmax safe
            lsum += e;
#pragma unroll
            for (int j = 0; j < 4; ++j) {
                int src = (j >> 1) | ((j & 1) << 1);
                float wf = __int_as_float(
                    __builtin_amdgcn_readlane(__float_as_int(e), src));
#pragma unroll
                for (int c = 0; c < 8; ++c)
                    acc[j][c] = fmaf(wf, xv[r][c], acc[j][c]);
            }
        }
    };

    auto loadrow = [&](int r, float4* dst) {
        int rc = r < hrows ? r : hrows - 1;  // clamped
        dst[0] = *(const float4*)(xp + (size_t)rc * C_ + lo);
        dst[1] = *(const float4*)(xp + (size_t)rc * C_ + hi);
    };

    float4 A[4][2], Bv[4][2];
#pragma unroll
    for (int r = 0; r < 4; ++r) loadrow(r, A[r]);
#pragma unroll
    for (int r = 0; r < 4; ++r) loadrow(4 + r, Bv[r]);

#pragma unroll 1
    for (int i = 0; i < hrows; i += 8) {
        process(A);                                   // rows i..i+3
#pragma unroll
        for (int r = 0; r < 4; ++r) loadrow(i + 8 + r, A[r]);
        process(Bv);                                  // rows i+4..i+7
#pragma unroll
        for (int r = 0; r < 4; ++r) loadrow(i + 12 + r, Bv[r]);
    }

    // per-wave l values for its 4 heads (wave-uniform)
    float lw[4];
#pragma unroll
    for (int j = 0; j < 4; ++j) {
        int src = (j >> 1) | ((j & 1) << 1);
        lw[j] = __int_as_float(__builtin_amdgcn_readlane(__float_as_int(lsum), src));
    }

    // block-combine: waves 0,1 own sacc rows 0-3; waves 2,3 rows 4-7.
    __shared__ float sacc[8 * 512];
    __shared__ float sl[8];
    for (int w = 0; w < 4; ++w) {
        if (wave == w) {
            bool first = (w & 1) == 0;  // waves 0,2 write; 1,3 add
#pragma unroll
            for (int j = 0; j < 4; ++j) {
                int h = 4 * g + j;
                float4 vlo = {acc[j][0], acc[j][1], acc[j][2], acc[j][3]};
                float4 vhi = {acc[j][4], acc[j][5], acc[j][6], acc[j][7]};
                float4* d0 = (float4*)&sacc[h * C_ + lo];
                float4* d1 = (float4*)&sacc[h * C_ + hi];
                if (first) { d0[0] = vlo; d1[0] = vhi; }
                else {
                    float4 a0 = d0[0], a1 = d1[0];
                    a0.x += vlo.x; a0.y += vlo.y; a0.z += vlo.z; a0.w += vlo.w;
                    a1.x += vhi.x; a1.y += vhi.y; a1.z += vhi.z; a1.w += vhi.w;
                    d0[0] = a0; d1[0] = a1;
                }
            }
            if (lane == 0) {
#pragma unroll
                for (int j = 0; j < 4; ++j) {
                    int h = 4 * g + j;
                    if (first) sl[h] = lw[j]; else sl[h] += lw[j];
                }
            }
        }
        __syncthreads();
    }

    float* pb = part + (size_t)blk * 4104;
    if (threadIdx.x < 8) pb[threadIdx.x] = sl[threadIdx.x];
    float* pa = pb + 8;
    for (int k = threadIdx.x; k < 4096; k += 256) pa[k] = sacc[k];
}

// ---------------- K4: reduce partials -> aa (unnormalized), Linv ----------------
__global__ void k_reduce(const float* __restrict__ part, float* __restrict__ ws, int CH) {
    int b = blockIdx.x >> 4, cc = blockIdx.x & 15, t = threadIdx.x;
    int h = t >> 5, c = cc * 32 + (t & 31);
    const float* pb = part + (size_t)b * CH * 4104;
    float s = 0.f;
    for (int p = 0; p < CH; ++p) s += pb[(size_t)p * 4104 + 8 + h * C_ + c];
    ws[WS_AA + b * 4096 + h * C_ + c] = s;
    if (cc == 0 && t < 8) {
        float ls = 0.f;
        for (int p = 0; p < CH; ++p) ls += pb[(size_t)p * 4104 + t];
        ws[WS_LINV + b * 8 + t] = 1.f / ls;
    }
}

// ---------------- K5: pooled (c-split halves) = Linv * aa @ Wv ----------------
__global__ void k_proj1(const float* __restrict__ ws, const float* __restrict__ Wv,
                        float* __restrict__ pp) {
    int gid = blockIdx.x * 256 + threadIdx.x;  // [0, 16384)
    int half = gid >> 13;
    int r = gid & 8191;
    int b = r >> 9, o = r & 511, h = o >> 6;
    const float* aa = ws + WS_AA + b * 4096 + h * C_;
    float Li = ws[WS_LINV + b * 8 + h];
    int c0 = half * 256;
    float s = 0.f;
#pragma unroll 8
    for (int c = 0; c < 256; ++c)
        s = fmaf(aa[c0 + c], Wv[(size_t)(c0 + c) * C_ + o], s);
    pp[half * 8192 + r] = s * Li;
}

// ---------------- K6: out = pooled @ Wp + bp ----------------
__global__ void k_proj2(const float* __restrict__ ws, const float* __restrict__ Wp,
                        const float* __restrict__ bp, float* __restrict__ out) {
    int gid = blockIdx.x * 256 + threadIdx.x;  // [0, 8192)
    int b = gid >> 9, o = gid & 511;
    const float* pp = ws + WS_PP + b * 512;
    float s = bp[o];
#pragma unroll 8
    for (int c = 0; c < 512; ++c) {
        float pc = pp[c] + pp[8192 + c];
        s = fmaf(pc, Wp[(size_t)c * C_ + o], s);
    }
    out[(size_t)b * C_ + o] = s;
}

extern "C" void kernel_launch(void* const* d_in, const int* in_sizes, int n_in,
                              void* d_out, int out_size, void* d_ws, size_t ws_size,
                              hipStream_t stream) {
    const float* x   = (const float*)d_in[0];
    const float* cls = (const float*)d_in[1];
    const float* Wq  = (const float*)d_in[2];
    const float* Wk  = (const float*)d_in[3];
    const float* Wv  = (const float*)d_in[4];
    const float* Wp  = (const float*)d_in[5];
    const float* bp  = (const float*)d_in[6];
    float* out = (float*)d_out;
    float* ws  = (float*)d_ws;

    int CH = CH_;
    while (CH > 1 && (size_t)(WS_PART + (size_t)B_ * CH * 4104) * 4 > ws_size) CH >>= 1;

    k_qfull<<<8, 256, 0, stream>>>(cls, Wq, ws);
    k_qk<<<64, 256, 0, stream>>>(Wk, ws);
    k_main<<<B_ * CH, 256, 0, stream>>>(x, ws, ws + WS_PART, CH);
    k_reduce<<<B_ * 16, 256, 0, stream>>>(ws + WS_PART, ws, CH);
    k_proj1<<<64, 256, 0, stream>>>(ws, Wv, ws + WS_PP);
    k_proj2<<<32, 256, 0, stream>>>(ws, Wp, bp, out);
}